// Round 1
// baseline (9677.408 us; speedup 1.0000x reference)
//
#include <hip/hip_runtime.h>

#define BB 16
#define KD 128
#define ND 8000
#define DD 256
#define LMB 1000.0f

// ---------------- K1: projection  sdescr[b][k][d] = sum_n pinv[b][k][n]*descr[b][d][n]
// grid (16, 8 slices, 2 tensors), block 1024. Tile: all 128 k x all 256 d, n-chunks of 40.
#define CH 40
#define CHW 44   // padded LDS row stride in words (44%32=12 -> full-bank-sweep b128 pattern)
#define NSL 8
#define NRG 1000
#define NCHK 25

__global__ __launch_bounds__(1024) void proj_kernel(
    const float* __restrict__ pinv_a, const float* __restrict__ descr_a,
    const float* __restrict__ pinv_b, const float* __restrict__ descr_b,
    float* __restrict__ sd_a, float* __restrict__ sd_b)
{
    const int b = blockIdx.x, slice = blockIdx.y, which = blockIdx.z;
    const float* P  = (which ? pinv_b  : pinv_a)  + (size_t)b * KD * ND;
    const float* Dm = (which ? descr_b : descr_a) + (size_t)b * DD * ND;
    float* outp = (which ? sd_b : sd_a) + (size_t)b * KD * DD;

    __shared__ float kbuf[KD][CHW];
    __shared__ float dbuf[DD][CHW];

    const int tid = threadIdx.x;
    const int tk = tid >> 5, td = tid & 31;

    // staging plan: 3840 float4 per chunk; u=0..2 always valid, u=3 only tid<768
    const float* gsrc[4];
    float* ldst[4];
    const bool v3 = (tid < 768);
    #pragma unroll
    for (int u = 0; u < 4; ++u) {
        int i = tid + u * 1024;
        if (i < 3840) {
            if (i < 1280) {
                int r = i / 10, c = i % 10;
                gsrc[u] = P + (size_t)r * ND + c * 4;
                ldst[u] = &kbuf[r][c * 4];
            } else {
                int j = i - 1280;
                int r = j / 10, c = j % 10;
                gsrc[u] = Dm + (size_t)r * ND + c * 4;
                ldst[u] = &dbuf[r][c * 4];
            }
        } else { gsrc[u] = P; ldst[u] = &kbuf[0][0]; }
    }
    float4 pf0, pf1, pf2, pf3;

    float acc[4][8];
    #pragma unroll
    for (int i = 0; i < 4; ++i)
        #pragma unroll
        for (int j = 0; j < 8; ++j) acc[i][j] = 0.f;

    const int n0 = slice * NRG;
    // preload + store chunk 0
    pf0 = *(const float4*)(gsrc[0] + n0);
    pf1 = *(const float4*)(gsrc[1] + n0);
    pf2 = *(const float4*)(gsrc[2] + n0);
    if (v3) pf3 = *(const float4*)(gsrc[3] + n0);
    *(float4*)ldst[0] = pf0;
    *(float4*)ldst[1] = pf1;
    *(float4*)ldst[2] = pf2;
    if (v3) *(float4*)ldst[3] = pf3;
    __syncthreads();

    for (int ch = 0; ch < NCHK; ++ch) {
        if (ch + 1 < NCHK) {
            int nb = n0 + (ch + 1) * CH;
            pf0 = *(const float4*)(gsrc[0] + nb);
            pf1 = *(const float4*)(gsrc[1] + nb);
            pf2 = *(const float4*)(gsrc[2] + nb);
            if (v3) pf3 = *(const float4*)(gsrc[3] + nb);
        }
        #pragma unroll
        for (int n4 = 0; n4 < 10; ++n4) {
            float4 kv[4], dv[8];
            #pragma unroll
            for (int i = 0; i < 4; ++i) kv[i] = *(const float4*)&kbuf[tk + 32 * i][n4 * 4];
            #pragma unroll
            for (int j = 0; j < 8; ++j) dv[j] = *(const float4*)&dbuf[td + 32 * j][n4 * 4];
            #pragma unroll
            for (int i = 0; i < 4; ++i)
                #pragma unroll
                for (int j = 0; j < 8; ++j)
                    acc[i][j] += kv[i].x * dv[j].x + kv[i].y * dv[j].y
                               + kv[i].z * dv[j].z + kv[i].w * dv[j].w;
        }
        __syncthreads();
        if (ch + 1 < NCHK) {
            *(float4*)ldst[0] = pf0;
            *(float4*)ldst[1] = pf1;
            *(float4*)ldst[2] = pf2;
            if (v3) *(float4*)ldst[3] = pf3;
        }
        __syncthreads();
    }

    #pragma unroll
    for (int i = 0; i < 4; ++i)
        #pragma unroll
        for (int j = 0; j < 8; ++j)
            atomicAdd(&outp[(size_t)(tk + 32 * i) * DD + td + 32 * j], acc[i][j]);
}

// ---------------- K2: masks (lambda folded in).  lm_ab[b][i][k] from (gb=eb[i], ga=ea[k])
__global__ __launch_bounds__(256) void mask_kernel(
    const float* __restrict__ ea_g, const float* __restrict__ eb_g,
    float* __restrict__ lm_ab, float* __restrict__ lm_ba)
{
    const int b = blockIdx.x, tid = threadIdx.x;
    __shared__ float ta[KD], ua[KD], tb[KD], ub[KD];
    __shared__ float red[256];
    float e = (tid < KD) ? ea_g[b * KD + tid] : eb_g[b * KD + (tid - KD)];
    red[tid] = e;
    __syncthreads();
    for (int s = 128; s > 0; s >>= 1) {
        if (tid < s) red[tid] = fmaxf(red[tid], red[tid + s]);
        __syncthreads();
    }
    float is = 1.0f / red[0];
    float g = e * is;
    float den = 1.0f / (g * g + 1.0f);
    if (tid < KD) { ta[tid] = g * den; ua[tid] = den; }
    else          { tb[tid - KD] = g * den; ub[tid - KD] = den; }
    __syncthreads();
    for (int idx = tid; idx < KD * KD; idx += 256) {
        int i = idx >> 7, kc = idx & 127;
        float re = tb[i] - ta[kc], im = ub[i] - ua[kc];
        lm_ab[(size_t)b * KD * KD + idx] = LMB * (re * re + im * im);
        float re2 = ta[i] - tb[kc], im2 = ua[i] - ub[kc];
        lm_ba[(size_t)b * KD * KD + idx] = LMB * (re2 * re2 + im2 * im2);
    }
}

// ---------------- K3: Grams. m=0: AA_aa(Sa,Sa) m=1: AA_bb(Sb,Sb) m=2: AA_ba(Sb,Sa)
// AA[m][b][k][l] = sum_d X[k][d]*Y[l][d]
__global__ __launch_bounds__(1024) void gram_kernel(
    const float* __restrict__ sd_a, const float* __restrict__ sd_b,
    float* __restrict__ AA)
{
    const int b = blockIdx.x, m = blockIdx.y;
    const float* X = (m == 0) ? sd_a : sd_b;
    const float* Y = (m == 2) ? sd_a : X;
    X += (size_t)b * KD * DD;
    Y += (size_t)b * KD * DD;
    float* outp = AA + ((size_t)m * BB + b) * KD * KD;

    __shared__ float Xs[KD][68], Ys[KD][68];
    const int tid = threadIdx.x;
    const int kq = tid >> 5, lq = tid & 31;
    float acc[4][4];
    #pragma unroll
    for (int i = 0; i < 4; ++i)
        #pragma unroll
        for (int j = 0; j < 4; ++j) acc[i][j] = 0.f;

    for (int chn = 0; chn < 4; ++chn) {
        int d0 = chn * 64;
        #pragma unroll
        for (int u = 0; u < 4; ++u) {
            int i = tid + u * 1024;           // 4096 float4s: X 2048 then Y 2048
            int half = i >> 11, rem = i & 2047;
            int r = rem >> 4, c = rem & 15;
            const float* src = half ? Y : X;
            float4 v = *(const float4*)(src + (size_t)r * DD + d0 + c * 4);
            if (half) *(float4*)&Ys[r][c * 4] = v;
            else      *(float4*)&Xs[r][c * 4] = v;
        }
        __syncthreads();
        #pragma unroll
        for (int d4 = 0; d4 < 16; ++d4) {
            float4 xv[4], yv[4];
            #pragma unroll
            for (int i = 0; i < 4; ++i) xv[i] = *(const float4*)&Xs[kq + 32 * i][d4 * 4];
            #pragma unroll
            for (int j = 0; j < 4; ++j) yv[j] = *(const float4*)&Ys[lq + 32 * j][d4 * 4];
            #pragma unroll
            for (int i = 0; i < 4; ++i)
                #pragma unroll
                for (int j = 0; j < 4; ++j)
                    acc[i][j] += xv[i].x * yv[j].x + xv[i].y * yv[j].y
                               + xv[i].z * yv[j].z + xv[i].w * yv[j].w;
        }
        __syncthreads();
    }
    #pragma unroll
    for (int i = 0; i < 4; ++i)
        #pragma unroll
        for (int j = 0; j < 4; ++j)
            outp[(size_t)(kq + 32 * i) * KD + lq + 32 * j] = acc[i][j];
}

// ---------------- K4: Gauss-Jordan in-place inversion (SPD, no pivoting).
// grid (16, 2): which=0 -> inv(AA_aa), which=1 -> inv(AA_bb). 512 threads.
__global__ __launch_bounds__(512) void invert_kernel(
    const float* __restrict__ AA, float* __restrict__ Hout)
{
    const int b = blockIdx.x, which = blockIdx.y;
    const float* src = AA + ((size_t)which * BB + b) * KD * KD;
    float* dst = Hout + ((size_t)which * BB + b) * KD * KD;
    __shared__ float A[KD][KD + 1];
    const int tid = threadIdx.x;
    for (int u = 0; u < 32; ++u) {
        int i = tid + u * 512;
        A[i >> 7][i & 127] = src[i];
    }
    __syncthreads();
    const int c = tid & 127, igrp = tid >> 7;
    for (int j = 0; j < 128; ++j) {
        float pv = 1.0f / A[j][j];
        if (tid < 128 && tid != j) A[tid][j] = -A[tid][j] * pv;  // phase 1: column j
        __syncthreads();
        float rowv = A[j][c];
        if (c != j) {                                            // phase 2: rank-1 update
            int i0 = igrp * 32;
            #pragma unroll 8
            for (int t = 0; t < 32; ++t) {
                int i = i0 + t;
                if (i != j) A[i][c] += A[i][j] * rowv;
            }
        }
        __syncthreads();
        if (tid < 128) A[j][tid] = (tid == j) ? pv : A[j][tid] * pv;  // phase 3: row j
        __syncthreads();
    }
    for (int u = 0; u < 32; ++u) {
        int i = tid + u * 512;
        dst[i] = A[i >> 7][i & 127];
    }
}

// ---------------- K5: Neumann-series solve.
// which=0 (fmap_12): H=inv(AA_aa), lm=lm_ab, r_i = AA_ba[b][i][:]
// which=1 (fmap_21): H=inv(AA_bb), lm=lm_ba, r_i = AA_ba[b][:][i]
// x_i = sum_t (-1)^t (H*lmD_i)^t H r_i ; out[b][i][l] = x_i[l]
#define NTERMS 6
__global__ __launch_bounds__(512) void solve_kernel(
    const float* __restrict__ AAba, const float* __restrict__ lm_ab,
    const float* __restrict__ lm_ba, const float* __restrict__ Hmat,
    float* __restrict__ outp)
{
    const int b = blockIdx.x, cg = blockIdx.y, which = blockIdx.z;
    const float* Hm = Hmat + ((size_t)which * BB + b) * KD * KD;
    const float* lm = (which ? lm_ba : lm_ab) + (size_t)b * KD * KD;
    const float* Rs = AAba + (size_t)b * KD * KD;
    float* op = outp + ((size_t)which * BB + b) * KD * KD;
    const int i0 = cg * 32;

    __shared__ float Hs[KD][132];       // Hs[d][l]; H symmetric so Hs[d][l] == H[l][d]
    __shared__ float Zc[2][32][132];    // Zc[buf][ic][d]
    __shared__ float lms[32][132];      // lms[ic][l]

    const int tid = threadIdx.x;
    const int rq = tid & 31;            // rows l = rq*4 + rr
    const int cq = tid >> 5;            // 0..15, cols ic = cq*2 + cc

    #pragma unroll
    for (int u = 0; u < 8; ++u) {
        int idx = tid + u * 512;
        int d = idx >> 5, l4 = idx & 31;
        *(float4*)&Hs[d][l4 * 4] = *(const float4*)(Hm + (size_t)d * KD + l4 * 4);
    }
    #pragma unroll
    for (int u = 0; u < 8; ++u) {
        int idx = tid + u * 512;
        int ic = idx >> 7, l = idx & 127;
        lms[ic][l] = lm[(size_t)(i0 + ic) * KD + l];
    }
    if (which == 0) {
        #pragma unroll
        for (int u = 0; u < 8; ++u) {
            int idx = tid + u * 512;
            int ic = idx >> 7, d = idx & 127;
            Zc[0][ic][d] = Rs[(size_t)(i0 + ic) * KD + d];
        }
    } else {
        #pragma unroll
        for (int u = 0; u < 8; ++u) {
            int idx = tid + u * 512;
            int d = idx >> 5, ic = idx & 31;
            Zc[0][ic][d] = Rs[(size_t)d * KD + i0 + ic];
        }
    }
    __syncthreads();

    float xacc[4][2];
    #pragma unroll
    for (int rr = 0; rr < 4; ++rr) { xacc[rr][0] = 0.f; xacc[rr][1] = 0.f; }
    int cur = 0;
    for (int t = 0; t < NTERMS; ++t) {
        float zr[4][2];
        #pragma unroll
        for (int rr = 0; rr < 4; ++rr) { zr[rr][0] = 0.f; zr[rr][1] = 0.f; }
        #pragma unroll 8
        for (int d4 = 0; d4 < 32; ++d4) {
            float4 hv[4];
            #pragma unroll
            for (int dd = 0; dd < 4; ++dd)
                hv[dd] = *(const float4*)&Hs[d4 * 4 + dd][rq * 4];
            float4 wv[2];
            #pragma unroll
            for (int cc = 0; cc < 2; ++cc)
                wv[cc] = *(const float4*)&Zc[cur][cq * 2 + cc][d4 * 4];
            #pragma unroll
            for (int cc = 0; cc < 2; ++cc) {
                zr[0][cc] += hv[0].x * wv[cc].x + hv[1].x * wv[cc].y + hv[2].x * wv[cc].z + hv[3].x * wv[cc].w;
                zr[1][cc] += hv[0].y * wv[cc].x + hv[1].y * wv[cc].y + hv[2].y * wv[cc].z + hv[3].y * wv[cc].w;
                zr[2][cc] += hv[0].z * wv[cc].x + hv[1].z * wv[cc].y + hv[2].z * wv[cc].z + hv[3].z * wv[cc].w;
                zr[3][cc] += hv[0].w * wv[cc].x + hv[1].w * wv[cc].y + hv[2].w * wv[cc].z + hv[3].w * wv[cc].w;
            }
        }
        const float s = (t & 1) ? -1.f : 1.f;
        #pragma unroll
        for (int rr = 0; rr < 4; ++rr) {
            xacc[rr][0] += s * zr[rr][0];
            xacc[rr][1] += s * zr[rr][1];
        }
        if (t + 1 < NTERMS) {
            #pragma unroll
            for (int cc = 0; cc < 2; ++cc) {
                float4 lmv = *(const float4*)&lms[cq * 2 + cc][rq * 4];
                float4 w;
                w.x = lmv.x * zr[0][cc];
                w.y = lmv.y * zr[1][cc];
                w.z = lmv.z * zr[2][cc];
                w.w = lmv.w * zr[3][cc];
                *(float4*)&Zc[cur ^ 1][cq * 2 + cc][rq * 4] = w;
            }
            __syncthreads();
            cur ^= 1;
        }
    }
    #pragma unroll
    for (int cc = 0; cc < 2; ++cc) {
        float4 o;
        o.x = xacc[0][cc]; o.y = xacc[1][cc]; o.z = xacc[2][cc]; o.w = xacc[3][cc];
        *(float4*)(op + (size_t)(i0 + cq * 2 + cc) * KD + rq * 4) = o;
    }
}

extern "C" void kernel_launch(void* const* d_in, const int* in_sizes, int n_in,
                              void* d_out, int out_size, void* d_ws, size_t ws_size,
                              hipStream_t stream) {
    (void)in_sizes; (void)n_in; (void)out_size; (void)ws_size;
    const float* evals_a = (const float*)d_in[0];
    const float* pinv_a  = (const float*)d_in[1];
    const float* descr_a = (const float*)d_in[2];
    const float* evals_b = (const float*)d_in[3];
    const float* pinv_b  = (const float*)d_in[4];
    const float* descr_b = (const float*)d_in[5];
    float* out = (float*)d_out;
    float* ws = (float*)d_ws;

    const size_t SD = (size_t)BB * KD * DD;   // 524288
    const size_t MM = (size_t)BB * KD * KD;   // 262144
    float* sd_a  = ws;
    float* sd_b  = sd_a + SD;
    float* AA    = sd_b + SD;        // 3*MM: [0]=AA_aa [1]=AA_bb [2]=AA_ba
    float* lm_ab = AA + 3 * MM;
    float* lm_ba = lm_ab + MM;
    float* Hm    = lm_ba + MM;       // 2*MM

    hipMemsetAsync(sd_a, 0, 2 * SD * sizeof(float), stream);
    proj_kernel<<<dim3(BB, NSL, 2), 1024, 0, stream>>>(pinv_a, descr_a, pinv_b, descr_b, sd_a, sd_b);
    mask_kernel<<<dim3(BB), 256, 0, stream>>>(evals_a, evals_b, lm_ab, lm_ba);
    gram_kernel<<<dim3(BB, 3), 1024, 0, stream>>>(sd_a, sd_b, AA);
    invert_kernel<<<dim3(BB, 2), 512, 0, stream>>>(AA, Hm);
    solve_kernel<<<dim3(BB, 4, 2), 512, 0, stream>>>(AA + 2 * MM, lm_ab, lm_ba, Hm, out);
}